// Round 4
// baseline (282.966 us; speedup 1.0000x reference)
//
#include <hip/hip_runtime.h>
#include <hip/hip_bf16.h>

// Problem constants (from reference)
#define T_DIM   16
#define N_NODES 10000
#define FIN     32
#define FH      64
#define NE      160000
#define GPB     8              // 32-lane groups per 256-thread block
#define TB      2              // timesteps per chunk
#define NCHUNK  (T_DIM / TB)   // 8 chunks -> one per XCD via bid%8
#define NF      (N_NODES * FIN)

// Broadcast lane f's value to all 32 lanes of each half-wave group.
// ds_swizzle BitMode: new_lane = (lane & and) | or  -> and=0, or=f.
#define BCAST(v, f) __int_as_float(__builtin_amdgcn_ds_swizzle(__float_as_int(v), ((f) << 5)))

// Dense-phase steps (f, j are compile-time constants via macro repetition)
#define DH(f) { float af0 = BCAST(a0, f), af1 = BCAST(a1, f);            \
                float2 w = W1p[(f) * 32 + lane];                          \
                h0 = fmaf(af0, w.x, h0); h1 = fmaf(af0, w.y, h1);         \
                h2 = fmaf(af1, w.x, h2); h3 = fmaf(af1, w.y, h3); }
#define DG(j) { float2 w = W2p[(j) * 32 + lane];                          \
                g0 = fmaf(BCAST(r0, j), w.x, g0);                         \
                g0 = fmaf(BCAST(r1, j), w.y, g0);                         \
                g1 = fmaf(BCAST(r2, j), w.x, g1);                         \
                g1 = fmaf(BCAST(r3, j), w.y, g1); }
#define REP8(M, b) M(b) M(b+1) M(b+2) M(b+3) M(b+4) M(b+5) M(b+6) M(b+7)
#define REP32(M) REP8(M, 0) REP8(M, 8) REP8(M, 16) REP8(M, 24)

// ---------------------------------------------------------------------------
// Kernel 1: degree (float, weighted, over dst) + in-edge count histogram
// ---------------------------------------------------------------------------
__global__ void build_deg_kernel(const int* __restrict__ ei,
                                 const float* __restrict__ w,
                                 float* __restrict__ deg,
                                 int* __restrict__ cnt) {
    int e = blockIdx.x * blockDim.x + threadIdx.x;
    if (e < NE) {
        int d = ei[NE + e];          // dst row of edge_index (2, E)
        atomicAdd(&deg[d], w[e]);
        atomicAdd(&cnt[d], 1);
    }
}

// ---------------------------------------------------------------------------
// Kernel 2 (merged): blocks 0-9 finish_deg; block 10 exclusive scan;
// blocks 11-12 pack W1/W2 into per-lane float2 column pairs.
// ---------------------------------------------------------------------------
__global__ __launch_bounds__(1024) void mid_kernel(
    const float* __restrict__ deg, float* __restrict__ dis,
    float* __restrict__ selfn,
    const int* __restrict__ cnt, int* __restrict__ rowptr,
    const float* __restrict__ W1, const float* __restrict__ W2,
    float2* __restrict__ W1p, float2* __restrict__ W2p) {
    __shared__ int sm[1024];
    int b = blockIdx.x;
    int tid = threadIdx.x;
    if (b < 10) {                       // dis / selfnorm
        int n = b * 1024 + tid;
        if (n < N_NODES) {
            float d = deg[n] + 1.0f;    // + self-loop weight
            float r = rsqrtf(d);
            dis[n] = r;
            selfn[n] = r * r;
        }
    } else if (b == 10) {               // exclusive scan cnt -> rowptr
        int base = tid * 10;
        int v[10];
        int s = 0;
#pragma unroll
        for (int k = 0; k < 10; ++k) {
            int i = base + k;
            v[k] = (i < N_NODES) ? cnt[i] : 0;
            s += v[k];
        }
        sm[tid] = s;
        __syncthreads();
        for (int off = 1; off < 1024; off <<= 1) {
            int t = (tid >= off) ? sm[tid - off] : 0;
            __syncthreads();
            sm[tid] += t;
            __syncthreads();
        }
        int run = (tid > 0) ? sm[tid - 1] : 0;
#pragma unroll
        for (int k = 0; k < 10; ++k) {
            int i = base + k;
            if (i <= N_NODES) rowptr[i] = run;
            run += v[k];
        }
    } else if (b == 11) {               // W1p[f*32+l] = {W1[f][l], W1[f][l+32]}
        int f = tid >> 5, l = tid & 31;
        W1p[tid] = make_float2(W1[f * FH + l], W1[f * FH + 32 + l]);
    } else {                            // W2p[j*32+l] = {W2[j][l], W2[j+32][l]}
        int j = tid >> 5, l = tid & 31;
        W2p[tid] = make_float2(W2[j * FIN + l], W2[(j + 32) * FIN + l]);
    }
}

// ---------------------------------------------------------------------------
// Kernel 3: scatter edges into dst-sorted CSR, packed {col, norm-bits}
// ---------------------------------------------------------------------------
__global__ void build_csr_kernel(const int* __restrict__ ei,
                                 const float* __restrict__ w,
                                 const float* __restrict__ dis,
                                 const int* __restrict__ rowptr,
                                 int* __restrict__ cursor,
                                 int2* __restrict__ edges) {
    int e = blockIdx.x * blockDim.x + threadIdx.x;
    if (e < NE) {
        int s = ei[e];
        int d = ei[NE + e];
        int pos = rowptr[d] + atomicAdd(&cursor[d], 1);
        edges[pos] = make_int2(s, __float_as_int(dis[s] * w[e] * dis[d]));
    }
}

// ---------------------------------------------------------------------------
// Kernel 4 (fused layer 1): block = (t-chunk tc, node-block nb),
// blockIdx = nb*8 + tc pins chunk->XCD (per-XCD x slice 2.56 MB < 4 MB L2).
// One 32-lane group per node, TB=2 timesteps in registers. ZERO LDS usage:
//  - edges: coalesced per-lane load + __shfl broadcast (one L2 trip / 32 edges)
//  - dense: ds_swizzle lane-broadcasts + L1-resident packed weights
// No barriers; groups fully independent.
// ---------------------------------------------------------------------------
__global__ __launch_bounds__(256) void layer1_kernel(
    const float* __restrict__ x,
    const int* __restrict__ rowptr,
    const int2* __restrict__ edges,
    const float* __restrict__ selfn,
    const float2* __restrict__ W1p,
    const float* __restrict__ b1,
    const float2* __restrict__ W2p,
    float2* __restrict__ gp) {
    int b = blockIdx.x;
    int tc = b & (NCHUNK - 1);
    int nb = b >> 3;
    int tid = threadIdx.x;
    int grp = tid >> 5;
    int lane = tid & 31;
    int n = nb * GPB + grp;

    const float* x0 = x + (size_t)(tc * TB) * NF;   // slice t0; t0+1 at +NF

    float sn = selfn[n];
    float a0 = sn * x0[n * FIN + lane];
    float a1 = sn * x0[NF + n * FIN + lane];

    int e0 = rowptr[n], e1 = rowptr[n + 1];
    for (int base = e0; base < e1; base += 32) {
        int cnt = min(32, e1 - base);
        int2 me = make_int2(0, 0);
        if (lane < cnt) me = edges[base + lane];
#pragma unroll 4
        for (int k = 0; k < cnt; ++k) {
            int c = __shfl(me.x, k, 32);
            float v = __int_as_float(__shfl(me.y, k, 32));
            int off = c * FIN + lane;
            a0 = fmaf(v, x0[off], a0);
            a1 = fmaf(v, x0[NF + off], a1);
        }
    }

    // dense: h = relu(acc @ W1 + b1); g = h @ W2  (all in-register)
    float h0 = b1[lane];
    float h1 = b1[lane + 32];
    float h2 = h0, h3 = h1;
    REP32(DH)
    float r0 = fmaxf(h0, 0.0f), r1 = fmaxf(h1, 0.0f);
    float r2 = fmaxf(h2, 0.0f), r3 = fmaxf(h3, 0.0f);
    float g0 = 0.0f, g1 = 0.0f;
    REP32(DG)

    gp[(n * NCHUNK + tc) * 32 + lane] = make_float2(g0, g1);
}

// ---------------------------------------------------------------------------
// Kernel 5 (layer 2 aggregation): same decomposition; g packed float2 so each
// edge is ONE 8 B/lane load (256 B/group contiguous). out (T,N,F) + b2.
// ---------------------------------------------------------------------------
__global__ __launch_bounds__(256) void layer2_kernel(
    const float2* __restrict__ gp,
    const int* __restrict__ rowptr,
    const int2* __restrict__ edges,
    const float* __restrict__ selfn,
    const float* __restrict__ b2,
    float* __restrict__ out, int out_size) {
    int b = blockIdx.x;
    int tc = b & (NCHUNK - 1);
    int nb = b >> 3;
    int tid = threadIdx.x;
    int grp = tid >> 5;
    int lane = tid & 31;
    int n = nb * GPB + grp;

    float sn = selfn[n];
    float bb = b2[lane];
    float2 gs = gp[(n * NCHUNK + tc) * 32 + lane];
    float a0 = fmaf(sn, gs.x, bb);
    float a1 = fmaf(sn, gs.y, bb);

    int e0 = rowptr[n], e1 = rowptr[n + 1];
    for (int base = e0; base < e1; base += 32) {
        int cnt = min(32, e1 - base);
        int2 me = make_int2(0, 0);
        if (lane < cnt) me = edges[base + lane];
#pragma unroll 4
        for (int k = 0; k < cnt; ++k) {
            int c = __shfl(me.x, k, 32);
            float v = __int_as_float(__shfl(me.y, k, 32));
            float2 gv = gp[(c * NCHUNK + tc) * 32 + lane];
            a0 = fmaf(v, gv.x, a0);
            a1 = fmaf(v, gv.y, a1);
        }
    }

    int t0 = tc * TB;
    out[(size_t)t0 * NF + n * FIN + lane] = a0;
    out[(size_t)t0 * NF + NF + n * FIN + lane] = a1;

    // second tuple element (scalar 0) and any tail
    if (b == 0 && tid == 0) {
        for (int i = T_DIM * NF; i < out_size; ++i) out[i] = 0.0f;
    }
}

// ---------------------------------------------------------------------------
extern "C" void kernel_launch(void* const* d_in, const int* in_sizes, int n_in,
                              void* d_out, int out_size, void* d_ws, size_t ws_size,
                              hipStream_t stream) {
    const float* x  = (const float*)d_in[0];
    const int*   ei = (const int*)d_in[1];     // (2, E) int32: [src | dst]
    const float* w  = (const float*)d_in[2];
    // d_in[3] missing_mask: unused by reference math
    const float* W1 = (const float*)d_in[4];
    const float* b1 = (const float*)d_in[5];
    const float* W2 = (const float*)d_in[6];
    const float* b2 = (const float*)d_in[7];
    float* out = (float*)d_out;

    char* p = (char*)d_ws;
    float2* gp    = (float2*)p; p += sizeof(float2) * (size_t)N_NODES * NCHUNK * 32;
    // deg, cnt, cursor contiguous -> single memset
    float* deg    = (float*)p; p += sizeof(float) * N_NODES;
    int*   cnt    = (int*)p;   p += sizeof(int) * N_NODES;
    int*   cursor = (int*)p;   p += sizeof(int) * N_NODES;
    float* dis    = (float*)p; p += sizeof(float) * N_NODES;
    float* selfn  = (float*)p; p += sizeof(float) * N_NODES;
    int*   rowptr = (int*)p;   p += sizeof(int) * (N_NODES + 1);
    int2*  edges  = (int2*)p;  p += sizeof(int2) * NE;
    float2* W1p   = (float2*)p; p += sizeof(float2) * FIN * 32;
    float2* W2p   = (float2*)p; p += sizeof(float2) * 32 * FIN;

    hipMemsetAsync(deg, 0, sizeof(float) * N_NODES * 3, stream);

    build_deg_kernel<<<(NE + 255) / 256, 256, 0, stream>>>(ei, w, deg, cnt);
    mid_kernel<<<13, 1024, 0, stream>>>(deg, dis, selfn, cnt, rowptr,
                                        W1, W2, W1p, W2p);
    build_csr_kernel<<<(NE + 255) / 256, 256, 0, stream>>>(ei, w, dis, rowptr,
                                                           cursor, edges);
    layer1_kernel<<<(N_NODES / GPB) * NCHUNK, 256, 0, stream>>>(
        x, rowptr, edges, selfn, W1p, b1, W2p, gp);
    layer2_kernel<<<(N_NODES / GPB) * NCHUNK, 256, 0, stream>>>(
        gp, rowptr, edges, selfn, b2, out, out_size);
}